// Round 6
// baseline (429.115 us; speedup 1.0000x reference)
//
#include <hip/hip_runtime.h>

#define NSEG 4096
#define QSCALE 131072.0f          // 2^17 fixed-point scale
#define QINV   (1.0f / 131072.0f)

typedef unsigned long long u64;
typedef unsigned int u32;
typedef float f32x4 __attribute__((ext_vector_type(4)));
typedef float f32x2 __attribute__((ext_vector_type(2)));

// ---------------------------------------------------------------------------
// Pass 1 (exact-division): per-segment sum of exp(x), u64 fixed-point LDS
// atomics. Iterates rounds in REVERSE so the pass starts on whatever the
// previous (forward) norm pass left in L3, and ends holding the head rounds
// for the next forward pass. Software-pipelined (prefetch next round).
// ---------------------------------------------------------------------------
__global__ __launch_bounds__(1024) void dsp_reduce_x(
    const f32x4* __restrict__ xab4, const f32x4* __restrict__ xba4,
    const int2* __restrict__ src2, const int2* __restrict__ tar2,
    float* __restrict__ partials,   // [gridDim.x][16384] floats
    int rounds, int rs)             // rs = gridDim.x * 1024
{
    __shared__ u64 ls[2 * NSEG];    // ab at [0,4096), ba at [4096,8192)
    for (int i = threadIdx.x; i < 2 * NSEG; i += 1024) ls[i] = 0ull;
    __syncthreads();

    const int base = blockIdx.x * 1024 + threadIdx.x;
    int u = base + (rounds - 1) * rs;

    f32x4 a = xab4[u], b = xba4[u];
    int2 s = src2[u], t = tar2[u];

    for (int r = rounds - 1; r >= 0; --r) {
        int un = u - rs;
        f32x4 an, bn; int2 sn, tn;
        if (r > 0) { an = xab4[un]; bn = xba4[un]; sn = src2[un]; tn = tar2[un]; }

        u32 a0 = __float2uint_rn(__expf(a.x) * QSCALE);
        u32 a1 = __float2uint_rn(__expf(a.y) * QSCALE);
        u32 a2 = __float2uint_rn(__expf(a.z) * QSCALE);
        u32 a3 = __float2uint_rn(__expf(a.w) * QSCALE);
        atomicAdd(&ls[s.x], (u64)a0 | ((u64)a1 << 32));
        atomicAdd(&ls[s.y], (u64)a2 | ((u64)a3 << 32));

        u32 b0 = __float2uint_rn(__expf(b.x) * QSCALE);
        u32 b1 = __float2uint_rn(__expf(b.y) * QSCALE);
        u32 b2 = __float2uint_rn(__expf(b.z) * QSCALE);
        u32 b3 = __float2uint_rn(__expf(b.w) * QSCALE);
        atomicAdd(&ls[NSEG + t.x], (u64)b0 | ((u64)b1 << 32));
        atomicAdd(&ls[NSEG + t.y], (u64)b2 | ((u64)b3 << 32));

        u = un; a = an; b = bn; s = sn; t = tn;
    }
    __syncthreads();

    // NT flush: don't evict L3 input data between passes.
    f32x2* dst = (f32x2*)(partials + (size_t)blockIdx.x * (4 * NSEG));
    for (int i = threadIdx.x; i < 2 * NSEG; i += 1024) {
        u64 v = ls[i];
        f32x2 w = { (float)(u32)v * QINV, (float)(u32)(v >> 32) * QINV };
        __builtin_nontemporal_store(w, &dst[i]);
    }
}

// Generic fallback (grid-stride, bounds-checked) — used only if E isn't
// divisible by grid span.
__global__ __launch_bounds__(1024) void dsp_reduce_g(
    const f32x4* __restrict__ xab4, const f32x4* __restrict__ xba4,
    const int2* __restrict__ src2, const int2* __restrict__ tar2,
    float* __restrict__ partials, int Eh)
{
    __shared__ u64 ls[2 * NSEG];
    for (int i = threadIdx.x; i < 2 * NSEG; i += 1024) ls[i] = 0ull;
    __syncthreads();

    const int stride = gridDim.x * 1024;
    for (int u = blockIdx.x * 1024 + threadIdx.x; u < Eh; u += stride) {
        f32x4 a = xab4[u]; f32x4 b = xba4[u];
        int2 s = src2[u]; int2 t = tar2[u];
        u32 a0 = __float2uint_rn(__expf(a.x) * QSCALE);
        u32 a1 = __float2uint_rn(__expf(a.y) * QSCALE);
        u32 a2 = __float2uint_rn(__expf(a.z) * QSCALE);
        u32 a3 = __float2uint_rn(__expf(a.w) * QSCALE);
        atomicAdd(&ls[s.x], (u64)a0 | ((u64)a1 << 32));
        atomicAdd(&ls[s.y], (u64)a2 | ((u64)a3 << 32));
        u32 b0 = __float2uint_rn(__expf(b.x) * QSCALE);
        u32 b1 = __float2uint_rn(__expf(b.y) * QSCALE);
        u32 b2 = __float2uint_rn(__expf(b.z) * QSCALE);
        u32 b3 = __float2uint_rn(__expf(b.w) * QSCALE);
        atomicAdd(&ls[NSEG + t.x], (u64)b0 | ((u64)b1 << 32));
        atomicAdd(&ls[NSEG + t.y], (u64)b2 | ((u64)b3 << 32));
    }
    __syncthreads();

    f32x2* dst = (f32x2*)(partials + (size_t)blockIdx.x * (4 * NSEG));
    for (int i = threadIdx.x; i < 2 * NSEG; i += 1024) {
        u64 v = ls[i];
        f32x2 w = { (float)(u32)v * QINV, (float)(u32)(v >> 32) * QINV };
        __builtin_nontemporal_store(w, &dst[i]);
    }
}

// ---------------------------------------------------------------------------
// Pass 2: column-sum NB partial tables (NT reads), store reciprocals.
// ---------------------------------------------------------------------------
__global__ __launch_bounds__(256) void dsp_sum(
    const f32x4* __restrict__ partials, f32x4* __restrict__ rcp_out, int nb)
{
    int i = blockIdx.x * blockDim.x + threadIdx.x;   // 0..4095
    f32x4 acc = {0.f, 0.f, 0.f, 0.f};
    for (int p = 0; p < nb; ++p) {
        f32x4 v = __builtin_nontemporal_load(&partials[(size_t)p * NSEG + i]);
        acc += v;
    }
    f32x4 r;
    r.x = (acc.x > 0.f) ? 1.f / acc.x : 0.f;
    r.y = (acc.y > 0.f) ? 1.f / acc.y : 0.f;
    r.z = (acc.z > 0.f) ? 1.f / acc.z : 0.f;
    r.w = (acc.w > 0.f) ? 1.f / acc.w : 0.f;
    rcp_out[i] = r;
}

// ---------------------------------------------------------------------------
// Pass 3 (exact-division): normalize + write 3 outputs. FORWARD rounds
// (pairs with reduce's reverse for L3 reuse). rcp tables in LDS, pipelined,
// NT stores. LDS float layout: ab at [0,2*NSEG), ba at [2*NSEG,4*NSEG).
// ---------------------------------------------------------------------------
__global__ __launch_bounds__(1024) void dsp_norm_x(
    const f32x4* __restrict__ xab4, const f32x4* __restrict__ xba4,
    const int2* __restrict__ src2, const int2* __restrict__ tar2,
    const f32x4* __restrict__ rcp_tab,
    f32x4* __restrict__ out, int rounds, int rs, int Eh)
{
    __shared__ float ls[4 * NSEG];
    for (int i = threadIdx.x; i < NSEG; i += 1024)
        ((f32x4*)ls)[i] = rcp_tab[i];
    __syncthreads();

    const int base = blockIdx.x * 1024 + threadIdx.x;
    int u = base;

    f32x4 a = xab4[u], b = xba4[u];
    int2 s = src2[u], t = tar2[u];

    for (int r = 0; r < rounds; ++r) {
        int un = u + rs;
        f32x4 an, bn; int2 sn, tn;
        if (r + 1 < rounds) { an = xab4[un]; bn = xba4[un]; sn = src2[un]; tn = tar2[un]; }

        f32x2 ra0 = *(const f32x2*)&ls[2 * s.x];
        f32x2 ra1 = *(const f32x2*)&ls[2 * s.y];
        f32x2 rb0 = *(const f32x2*)&ls[2 * NSEG + 2 * t.x];
        f32x2 rb1 = *(const f32x2*)&ls[2 * NSEG + 2 * t.y];

        f32x4 zab = { __expf(a.x) * ra0.x, __expf(a.y) * ra0.y,
                      __expf(a.z) * ra1.x, __expf(a.w) * ra1.y };
        f32x4 zba = { __expf(b.x) * rb0.x, __expf(b.y) * rb0.y,
                      __expf(b.z) * rb1.x, __expf(b.w) * rb1.y };
        f32x4 prod = zab * zba;

        __builtin_nontemporal_store(prod, &out[u]);            // zab*zba
        __builtin_nontemporal_store(zab,  &out[Eh + u]);       // zab
        __builtin_nontemporal_store(zba,  &out[2 * Eh + u]);   // zba

        u = un; a = an; b = bn; s = sn; t = tn;
    }
}

// Generic fallback norm.
__global__ __launch_bounds__(1024) void dsp_norm_g(
    const f32x4* __restrict__ xab4, const f32x4* __restrict__ xba4,
    const int2* __restrict__ src2, const int2* __restrict__ tar2,
    const f32x4* __restrict__ rcp_tab,
    f32x4* __restrict__ out, int Eh)
{
    __shared__ float ls[4 * NSEG];
    for (int i = threadIdx.x; i < NSEG; i += 1024)
        ((f32x4*)ls)[i] = rcp_tab[i];
    __syncthreads();

    const int stride = gridDim.x * 1024;
    for (int u = blockIdx.x * 1024 + threadIdx.x; u < Eh; u += stride) {
        f32x4 a = xab4[u]; f32x4 b = xba4[u];
        int2 s = src2[u]; int2 t = tar2[u];
        f32x2 ra0 = *(const f32x2*)&ls[2 * s.x];
        f32x2 ra1 = *(const f32x2*)&ls[2 * s.y];
        f32x2 rb0 = *(const f32x2*)&ls[2 * NSEG + 2 * t.x];
        f32x2 rb1 = *(const f32x2*)&ls[2 * NSEG + 2 * t.y];
        f32x4 zab = { __expf(a.x) * ra0.x, __expf(a.y) * ra0.y,
                      __expf(a.z) * ra1.x, __expf(a.w) * ra1.y };
        f32x4 zba = { __expf(b.x) * rb0.x, __expf(b.y) * rb0.y,
                      __expf(b.z) * rb1.x, __expf(b.w) * rb1.y };
        f32x4 prod = zab * zba;
        __builtin_nontemporal_store(prod, &out[u]);
        __builtin_nontemporal_store(zab,  &out[Eh + u]);
        __builtin_nontemporal_store(zba,  &out[2 * Eh + u]);
    }
}

extern "C" void kernel_launch(void* const* d_in, const int* in_sizes, int n_in,
                              void* d_out, int out_size, void* d_ws, size_t ws_size,
                              hipStream_t stream)
{
    const int E  = in_sizes[0] / 2;
    const int Eh = E / 2;
    const f32x4* xab4 = (const f32x4*)d_in[0];
    const f32x4* xba4 = (const f32x4*)d_in[1];
    const int2*  src2 = (const int2*)d_in[2];
    const int2*  tar2 = (const int2*)d_in[3];

    const int NB = 512;                       // blocks (= partial count)
    const int RS = NB * 1024;                 // elements per grid round
    float* rcp_tab  = (float*)d_ws;           // 16384 floats
    float* partials = (float*)((char*)d_ws + 65536);
    size_t need = 65536 + (size_t)NB * 65536;
    const bool exact = (ws_size >= need) && (Eh % RS == 0) && (Eh / RS >= 1);

    if (exact) {
        const int rounds = Eh / RS;
        dsp_reduce_x<<<NB, 1024, 0, stream>>>(xab4, xba4, src2, tar2,
                                              partials, rounds, RS);
        dsp_sum<<<NSEG / 256, 256, 0, stream>>>((const f32x4*)partials,
                                                (f32x4*)rcp_tab, NB);
        dsp_norm_x<<<NB, 1024, 0, stream>>>(xab4, xba4, src2, tar2,
                                            (const f32x4*)rcp_tab,
                                            (f32x4*)d_out, rounds, RS, Eh);
    } else {
        dsp_reduce_g<<<NB, 1024, 0, stream>>>(xab4, xba4, src2, tar2,
                                              partials, Eh);
        dsp_sum<<<NSEG / 256, 256, 0, stream>>>((const f32x4*)partials,
                                                (f32x4*)rcp_tab, NB);
        dsp_norm_g<<<NB, 1024, 0, stream>>>(xab4, xba4, src2, tar2,
                                            (const f32x4*)rcp_tab,
                                            (f32x4*)d_out, Eh);
    }
}

// Round 7
// 356.924 us; speedup vs baseline: 1.2023x; 1.2023x over previous
//
#include <hip/hip_runtime.h>
#include <hip/hip_cooperative_groups.h>

namespace cg = cooperative_groups;

#define NSEG 4096
#define QSCALE 131072.0f          // 2^17 fixed-point scale
#define QINV   (1.0f / 131072.0f)
#define NB 512                    // cooperative grid blocks (= partial count)

typedef unsigned long long u64;
typedef unsigned int u32;
typedef float f32x4 __attribute__((ext_vector_type(4)));
typedef float f32x2 __attribute__((ext_vector_type(2)));

// ---------------------------------------------------------------------------
// Fused cooperative kernel: reduce -> (sync) -> table-sum -> (sync) -> norm.
// Phase A forward, phase C reverse: C starts on the tail that A just left in
// L3 (the only reuse window — harness poison fills evict L3 between replays).
// ---------------------------------------------------------------------------
__global__ __launch_bounds__(1024, 8) void dsp_fused(
    const f32x4* __restrict__ xab4, const f32x4* __restrict__ xba4,
    const int2* __restrict__ src2, const int2* __restrict__ tar2,
    float* __restrict__ partials,   // [NB][16384]
    float* __restrict__ rcp_tab,    // [16384] : ab at [0,8192), ba at [8192,16384)
    f32x4* __restrict__ out,
    int rounds, int rs, int Eh)
{
    __shared__ u64 ls[2 * NSEG];    // 64 KB; reused as float[4*NSEG] in phase C
    const int tid = threadIdx.x;
    const int bid = blockIdx.x;
    const int base = bid * 1024 + tid;

    // ---------------- Phase A: per-segment exp-sums (forward) ----------------
    for (int i = tid; i < 2 * NSEG; i += 1024) ls[i] = 0ull;
    __syncthreads();

    for (int r = 0; r < rounds; ++r) {
        int u = base + r * rs;
        f32x4 a = xab4[u];
        f32x4 b = xba4[u];
        int2 s = src2[u];
        int2 t = tar2[u];

        u32 a0 = __float2uint_rn(__expf(a.x) * QSCALE);
        u32 a1 = __float2uint_rn(__expf(a.y) * QSCALE);
        u32 a2 = __float2uint_rn(__expf(a.z) * QSCALE);
        u32 a3 = __float2uint_rn(__expf(a.w) * QSCALE);
        atomicAdd(&ls[s.x], (u64)a0 | ((u64)a1 << 32));
        atomicAdd(&ls[s.y], (u64)a2 | ((u64)a3 << 32));

        u32 b0 = __float2uint_rn(__expf(b.x) * QSCALE);
        u32 b1 = __float2uint_rn(__expf(b.y) * QSCALE);
        u32 b2 = __float2uint_rn(__expf(b.z) * QSCALE);
        u32 b3 = __float2uint_rn(__expf(b.w) * QSCALE);
        atomicAdd(&ls[NSEG + t.x], (u64)b0 | ((u64)b1 << 32));
        atomicAdd(&ls[NSEG + t.y], (u64)b2 | ((u64)b3 << 32));
    }
    __syncthreads();

    // Flush per-block partial table (normal stores: keep L2/L3 resident).
    {
        f32x2* dst = (f32x2*)(partials + (size_t)bid * (4 * NSEG));
        for (int i = tid; i < 2 * NSEG; i += 1024) {
            u64 v = ls[i];
            f32x2 w = { (float)(u32)v * QINV, (float)(u32)(v >> 32) * QINV };
            dst[i] = w;
        }
    }
    __threadfence();                 // push L2 so other XCDs see partials
    cg::this_grid().sync();

    // ------------- Phase B1: 32 table columns per block -> rcp --------------
    {
        int cl = tid >> 5;           // 0..31 : column within this block's chunk
        int k  = tid & 31;           // 0..31 : partial-stripe lane
        int col = bid * 32 + cl;     // 0..16383
        float acc = 0.f;
        for (int p = k; p < NB; p += 32)
            acc += partials[(size_t)p * (4 * NSEG) + col];
        for (int off = 16; off; off >>= 1)
            acc += __shfl_down(acc, off, 32);
        if (k == 0)
            rcp_tab[col] = (acc > 0.f) ? 1.f / acc : 0.f;
    }
    __threadfence();
    cg::this_grid().sync();

    // ------------- Phase B2: stage rcp table into LDS -----------------------
    float* lf = (float*)ls;
    for (int i = tid; i < NSEG; i += 1024)
        ((f32x4*)lf)[i] = ((const f32x4*)rcp_tab)[i];
    __syncthreads();

    // ---------------- Phase C: normalize (REVERSE rounds) -------------------
    for (int r = rounds - 1; r >= 0; --r) {
        int u = base + r * rs;
        f32x4 a = xab4[u];
        f32x4 b = xba4[u];
        int2 s = src2[u];
        int2 t = tar2[u];

        f32x2 ra0 = *(const f32x2*)&lf[2 * s.x];
        f32x2 ra1 = *(const f32x2*)&lf[2 * s.y];
        f32x2 rb0 = *(const f32x2*)&lf[2 * NSEG + 2 * t.x];
        f32x2 rb1 = *(const f32x2*)&lf[2 * NSEG + 2 * t.y];

        f32x4 zab = { __expf(a.x) * ra0.x, __expf(a.y) * ra0.y,
                      __expf(a.z) * ra1.x, __expf(a.w) * ra1.y };
        f32x4 zba = { __expf(b.x) * rb0.x, __expf(b.y) * rb0.y,
                      __expf(b.z) * rb1.x, __expf(b.w) * rb1.y };
        f32x4 prod = zab * zba;

        __builtin_nontemporal_store(prod, &out[u]);            // zab*zba
        __builtin_nontemporal_store(zab,  &out[Eh + u]);       // zab
        __builtin_nontemporal_store(zba,  &out[2 * Eh + u]);   // zba
    }
}

// ===========================================================================
// Fallback 3-kernel path (R5 structure) — used when cooperative residency or
// exact division is unavailable.
// ===========================================================================
__global__ __launch_bounds__(1024) void dsp_reduce_g(
    const f32x4* __restrict__ xab4, const f32x4* __restrict__ xba4,
    const int2* __restrict__ src2, const int2* __restrict__ tar2,
    float* __restrict__ partials, int Eh)
{
    __shared__ u64 ls[2 * NSEG];
    for (int i = threadIdx.x; i < 2 * NSEG; i += 1024) ls[i] = 0ull;
    __syncthreads();

    const int stride = gridDim.x * 1024;
    for (int u = blockIdx.x * 1024 + threadIdx.x; u < Eh; u += stride) {
        f32x4 a = xab4[u]; f32x4 b = xba4[u];
        int2 s = src2[u]; int2 t = tar2[u];
        u32 a0 = __float2uint_rn(__expf(a.x) * QSCALE);
        u32 a1 = __float2uint_rn(__expf(a.y) * QSCALE);
        u32 a2 = __float2uint_rn(__expf(a.z) * QSCALE);
        u32 a3 = __float2uint_rn(__expf(a.w) * QSCALE);
        atomicAdd(&ls[s.x], (u64)a0 | ((u64)a1 << 32));
        atomicAdd(&ls[s.y], (u64)a2 | ((u64)a3 << 32));
        u32 b0 = __float2uint_rn(__expf(b.x) * QSCALE);
        u32 b1 = __float2uint_rn(__expf(b.y) * QSCALE);
        u32 b2 = __float2uint_rn(__expf(b.z) * QSCALE);
        u32 b3 = __float2uint_rn(__expf(b.w) * QSCALE);
        atomicAdd(&ls[NSEG + t.x], (u64)b0 | ((u64)b1 << 32));
        atomicAdd(&ls[NSEG + t.y], (u64)b2 | ((u64)b3 << 32));
    }
    __syncthreads();

    f32x2* dst = (f32x2*)(partials + (size_t)blockIdx.x * (4 * NSEG));
    for (int i = threadIdx.x; i < 2 * NSEG; i += 1024) {
        u64 v = ls[i];
        f32x2 w = { (float)(u32)v * QINV, (float)(u32)(v >> 32) * QINV };
        dst[i] = w;
    }
}

__global__ __launch_bounds__(256) void dsp_sum(
    const f32x4* __restrict__ partials, f32x4* __restrict__ rcp_out, int nb)
{
    int i = blockIdx.x * blockDim.x + threadIdx.x;   // 0..4095
    f32x4 acc = {0.f, 0.f, 0.f, 0.f};
    for (int p = 0; p < nb; ++p)
        acc += partials[(size_t)p * NSEG + i];
    f32x4 r;
    r.x = (acc.x > 0.f) ? 1.f / acc.x : 0.f;
    r.y = (acc.y > 0.f) ? 1.f / acc.y : 0.f;
    r.z = (acc.z > 0.f) ? 1.f / acc.z : 0.f;
    r.w = (acc.w > 0.f) ? 1.f / acc.w : 0.f;
    rcp_out[i] = r;
}

__global__ __launch_bounds__(1024) void dsp_norm_g(
    const f32x4* __restrict__ xab4, const f32x4* __restrict__ xba4,
    const int2* __restrict__ src2, const int2* __restrict__ tar2,
    const f32x4* __restrict__ rcp_tab,
    f32x4* __restrict__ out, int Eh)
{
    __shared__ float ls[4 * NSEG];
    for (int i = threadIdx.x; i < NSEG; i += 1024)
        ((f32x4*)ls)[i] = rcp_tab[i];
    __syncthreads();

    const int stride = gridDim.x * 1024;
    for (int u = blockIdx.x * 1024 + threadIdx.x; u < Eh; u += stride) {
        f32x4 a = xab4[u]; f32x4 b = xba4[u];
        int2 s = src2[u]; int2 t = tar2[u];
        f32x2 ra0 = *(const f32x2*)&ls[2 * s.x];
        f32x2 ra1 = *(const f32x2*)&ls[2 * s.y];
        f32x2 rb0 = *(const f32x2*)&ls[2 * NSEG + 2 * t.x];
        f32x2 rb1 = *(const f32x2*)&ls[2 * NSEG + 2 * t.y];
        f32x4 zab = { __expf(a.x) * ra0.x, __expf(a.y) * ra0.y,
                      __expf(a.z) * ra1.x, __expf(a.w) * ra1.y };
        f32x4 zba = { __expf(b.x) * rb0.x, __expf(b.y) * rb0.y,
                      __expf(b.z) * rb1.x, __expf(b.w) * rb1.y };
        f32x4 prod = zab * zba;
        __builtin_nontemporal_store(prod, &out[u]);
        __builtin_nontemporal_store(zab,  &out[Eh + u]);
        __builtin_nontemporal_store(zba,  &out[2 * Eh + u]);
    }
}

extern "C" void kernel_launch(void* const* d_in, const int* in_sizes, int n_in,
                              void* d_out, int out_size, void* d_ws, size_t ws_size,
                              hipStream_t stream)
{
    const int E  = in_sizes[0] / 2;
    const int Eh = E / 2;
    const f32x4* xab4 = (const f32x4*)d_in[0];
    const f32x4* xba4 = (const f32x4*)d_in[1];
    const int2*  src2 = (const int2*)d_in[2];
    const int2*  tar2 = (const int2*)d_in[3];

    const int RS = NB * 1024;                 // elements per grid round
    float* rcp_tab  = (float*)d_ws;           // 16384 floats
    float* partials = (float*)((char*)d_ws + 65536);
    size_t need = 65536 + (size_t)NB * 65536;

    int rounds = Eh / RS;
    bool exact = (ws_size >= need) && (Eh % RS == 0) && (rounds >= 1);

    int occ = 0;
    (void)hipOccupancyMaxActiveBlocksPerMultiprocessor(&occ, dsp_fused, 1024, 0);

    if (exact && occ >= 2) {
        f32x4* outv = (f32x4*)d_out;
        void* args[] = { (void*)&xab4, (void*)&xba4, (void*)&src2, (void*)&tar2,
                         (void*)&partials, (void*)&rcp_tab, (void*)&outv,
                         (void*)&rounds, (void*)&(int&)RS, (void*)&(int&)Eh };
        int rs_v = RS, eh_v = Eh;
        args[7] = (void*)&rounds; args[8] = (void*)&rs_v; args[9] = (void*)&eh_v;
        (void)hipLaunchCooperativeKernel((void*)dsp_fused, dim3(NB), dim3(1024),
                                         args, 0, stream);
    } else {
        dsp_reduce_g<<<NB, 1024, 0, stream>>>(xab4, xba4, src2, tar2,
                                              partials, Eh);
        dsp_sum<<<NSEG / 256, 256, 0, stream>>>((const f32x4*)partials,
                                                (f32x4*)rcp_tab, NB);
        dsp_norm_g<<<NB, 1024, 0, stream>>>(xab4, xba4, src2, tar2,
                                            (const f32x4*)rcp_tab,
                                            (f32x4*)d_out, Eh);
    }
}